// Round 6
// baseline (310.653 us; speedup 1.0000x reference)
//
#include <hip/hip_runtime.h>
#include <hip/hip_bf16.h>
#include <stdint.h>

#define B_   4
#define H_   56
#define W_   56
#define C_   256
#define CR   64
#define G_   16
#define CG   16
#define KS   7
#define KK   49
#define PADR 3
#define NPX  (B_*H_*W_)   // 12544
#define NBLK 1024
#define MAGIC 0x9E37C0DE13572468ull

typedef __attribute__((ext_vector_type(8))) short bf16x8;
typedef __attribute__((ext_vector_type(4))) float f32x4;
typedef __attribute__((ext_vector_type(2))) float f32x2;

__device__ __forceinline__ uint32_t f2bf(float f) {          // RNE fp32->bf16 bits
    uint32_t x = __float_as_uint(f);
    return (x + 0x7fffu + ((x >> 16) & 1u)) >> 16;
}
__device__ __forceinline__ uint32_t pkbf(float a, float b) { // packed RNE: v_cvt_pk_bf16_f32
    union { __hip_bfloat162 h; uint32_t u; } c;
    c.h = __float22bfloat162_rn(make_float2(a, b));
    return c.u;                                              // a lo16, b hi16
}
__device__ __forceinline__ float blo(uint32_t w) { return __uint_as_float(w << 16); }
__device__ __forceinline__ float bhi(uint32_t w) { return __uint_as_float(w & 0xffff0000u); }

union U4V { uint4 u; bf16x8 v; };

// graph-capture-safe grid barrier: tid0 arrives (agent release), spins (agent acquire)
__device__ __forceinline__ void gbar(uint32_t* c, int tid) {
    __syncthreads();
    if (tid == 0) {
        __hip_atomic_fetch_add(c, 1u, __ATOMIC_ACQ_REL, __HIP_MEMORY_SCOPE_AGENT);
        while (__hip_atomic_load(c, __ATOMIC_ACQUIRE, __HIP_MEMORY_SCOPE_AGENT) < (uint32_t)NBLK)
            __builtin_amdgcn_s_sleep(2);
    }
    __syncthreads();
}

#define TS   14          // output tile edge
#define HS   20          // TS + KS - 1
#define XSP  21          // xs row pitch in 32B slots: 672B%128=32 -> bank quads rotate per row
#define KGW  56          // u16 per kg row: 7 kh * 8 slots (7 taps + 1 pad), 112B pitch

// ---------- single kernel: prepack -> GEMM1(r) -> kgen+involution ----------
// grid = 1024 blocks x 256 thr: exactly 4 blocks/CU (LDS 35.4KB<=40KB, VGPR capped 128)
__global__ __launch_bounds__(256, 4) void k_all(
        const float* __restrict__ x, const float* __restrict__ wr,
        const float* __restrict__ wspan,
        const float* __restrict__ gamma, const float* __restrict__ beta,
        const float* __restrict__ mean, const float* __restrict__ var,
        const float* __restrict__ bspan,
        uint16_t* __restrict__ r, uint16_t* __restrict__ wrp,
        uint16_t* __restrict__ wpp, float* __restrict__ scale,
        float* __restrict__ shift, uint8_t* sync, float* __restrict__ out) {
    __shared__ __align__(16) uint16_t xs[420 * 16];        // 13440 B (pitch-21 rows)
    __shared__ __align__(16) uint16_t kg[196 * KGW];       // 21952 B; rho = (pix>>1)+(pix&1)*98

    int tid  = threadIdx.x;
    int bid  = blockIdx.x;
    int lane = tid & 63, w = tid >> 6;

    // ======== phase 0: weight prepack (spread across all blocks, lane-coalesced) ========
    if (w == 0) {                       // wpp: 65536 = 1024 blocks * 64 lanes
        int idx = bid * 64 + lane;
        int j = idx & 7, fl = (idx >> 3) & 63, nb = (idx >> 9) & 3,
            kb = (idx >> 11) & 1, g = idx >> 12;
        int k = kb * 32 + (fl >> 4) * 8 + j;
        int n = nb * 16 + (fl & 15);
        float v = (n < KK) ? wspan[k * (KK * G_) + g * KK + n] : 0.f;
        wpp[idx] = (uint16_t)f2bf(v);
    } else if (w == 1 && bid < 256) {   // wrp: 16384 = 256 blocks * 64 lanes
        int idx = bid * 64 + lane;
        int j = idx & 7, fl = (idx >> 3) & 63, nb = (idx >> 9) & 3, kb = idx >> 11;
        int k = kb * 32 + (fl >> 4) * 8 + j;
        int n = nb * 16 + (fl & 15);
        wrp[idx] = (uint16_t)f2bf(wr[k * CR + n]);
    } else if (w == 2 && bid == 0) {    // BN fold: 64 channels
        float s = gamma[lane] * rsqrtf(var[lane] + 1e-3f);
        scale[lane] = s;
        shift[lane] = beta[lane] - mean[lane] * s;
    }

    // ======== init gate: make barrier counters poison-proof (ws is re-poisoned) ========
    uint64_t* magic = (uint64_t*)sync;
    uint32_t* ctr   = (uint32_t*)(sync + 8);
    if (tid == 0) {
        if (bid == 0) {
            if (__hip_atomic_load(magic, __ATOMIC_ACQUIRE, __HIP_MEMORY_SCOPE_AGENT) != MAGIC) {
                __hip_atomic_store(&ctr[0], 0u, __ATOMIC_RELAXED, __HIP_MEMORY_SCOPE_AGENT);
                __hip_atomic_store(&ctr[1], 0u, __ATOMIC_RELAXED, __HIP_MEMORY_SCOPE_AGENT);
                __hip_atomic_store(&ctr[2], 0u, __ATOMIC_RELAXED, __HIP_MEMORY_SCOPE_AGENT);
                __hip_atomic_store(magic, (uint64_t)MAGIC, __ATOMIC_RELEASE, __HIP_MEMORY_SCOPE_AGENT);
            }
        } else {
            while (__hip_atomic_load(magic, __ATOMIC_ACQUIRE, __HIP_MEMORY_SCOPE_AGENT) != MAGIC)
                __builtin_amdgcn_s_sleep(2);
        }
    }
    gbar(&ctr[0], tid);                 // barrier 1: phase-0 results visible grid-wide

    // ======== phase 1: r = relu(bn(x @ w_reduce)); 784 m-tiles over 4096 waves ====
    {
        int gw = bid * 4 + w;           // every 5th wave busy -> even load across CUs
        if (gw < 3920 && gw % 5 == 0) {
            int mt  = gw / 5;           // 0..783
            int pix = mt * 16 + (lane & 15);
            int ko  = (lane >> 4) * 8;
            const float* xrow = x + (size_t)pix * C_ + ko;
            float s4[4], sh4[4];
            #pragma unroll
            for (int nb = 0; nb < 4; ++nb) {
                int d = nb * 16 + (lane & 15);
                s4[nb] = scale[d];
                sh4[nb] = shift[d];
            }
            f32x4 acc[4] = {{0,0,0,0},{0,0,0,0},{0,0,0,0},{0,0,0,0}};
            #pragma unroll
            for (int kb = 0; kb < 8; ++kb) {         // K = 256 in steps of 32
                float4 a0 = *(const float4*)(xrow + kb * 32);
                float4 a1 = *(const float4*)(xrow + kb * 32 + 4);
                U4V af;
                af.u = make_uint4(pkbf(a0.x, a0.y), pkbf(a0.z, a0.w),
                                  pkbf(a1.x, a1.y), pkbf(a1.z, a1.w));
                const uint16_t* wb = wrp + kb * 2048 + lane * 8;
                #pragma unroll
                for (int nb = 0; nb < 4; ++nb) {
                    bf16x8 bf_ = *(const bf16x8*)(wb + nb * 512);
                    acc[nb] = __builtin_amdgcn_mfma_f32_16x16x32_bf16(af.v, bf_, acc[nb], 0, 0, 0);
                }
            }
            int rq = (lane >> 4) * 4;   // C: col=lane&15 (ch), row=(lane>>4)*4+reg (pixel)
            #pragma unroll
            for (int nb = 0; nb < 4; ++nb) {
                #pragma unroll
                for (int rg = 0; rg < 4; ++rg) {
                    float v = fmaf(acc[nb][rg], s4[nb], sh4[nb]);
                    v = v > 0.f ? v : 0.f;
                    r[(size_t)(mt * 16 + rq + rg) * CR + (nb * 16 + (lane & 15))] =
                        (uint16_t)f2bf(v);
                }
            }
        }
    }
    gbar(&ctr[1], tid);                 // barrier 2: r visible grid-wide

    // ======== phase 2: kgen (MFMA) + involution, one block per (tile, group, batch) ======
    int tile = bid & 15, g = (bid >> 4) & 15, b = bid >> 8;
    int ty0 = (tile >> 2) * TS, tx0 = (tile & 3) * TS;

    // issue weight/bias loads FIRST (hide under staging)
    bf16x8 bfr[2][4];
    const uint16_t* wb2 = wpp + g * 4096 + lane * 8;
    #pragma unroll
    for (int kb = 0; kb < 2; ++kb)
        #pragma unroll
        for (int nb = 0; nb < 4; ++nb)
            bfr[kb][nb] = *(const bf16x8*)(wb2 + kb * 2048 + nb * 512);
    float bias[4];
    #pragma unroll
    for (int nb = 0; nb < 4; ++nb) {
        int n = nb * 16 + (lane & 15);
        bias[nb] = (n < KK) ? bspan[g * KK + n] : 0.f;
    }

    // stage x group-slice (halo) straight from fp32 x (L2/L3-warm)
    #pragma unroll
    for (int pass = 0; pass < 2; ++pass) {
        int i = tid + pass * 256;
        if (i < HS * HS) {
            int py = i / HS, px = i % HS;
            int gy = ty0 + py - PADR, gx = tx0 + px - PADR;
            uint4 wA = make_uint4(0, 0, 0, 0), wB = wA;
            if (gy >= 0 && gy < H_ && gx >= 0 && gx < W_) {
                const float* xp = x + (((size_t)(b * H_ + gy)) * W_ + gx) * C_ + g * CG;
                float4 q0 = *(const float4*)(xp);
                float4 q1 = *(const float4*)(xp + 4);
                float4 q2 = *(const float4*)(xp + 8);
                float4 q3 = *(const float4*)(xp + 12);
                wA = make_uint4(pkbf(q0.x, q0.y), pkbf(q0.z, q0.w),
                                pkbf(q1.x, q1.y), pkbf(q1.z, q1.w));
                wB = make_uint4(pkbf(q2.x, q2.y), pkbf(q2.z, q2.w),
                                pkbf(q3.x, q3.y), pkbf(q3.z, q3.w));
            }
            uint16_t* dst = xs + (py * XSP + px) * 16;     // pitch-21 slots
            *(uint4*)(dst + 0) = wA;
            *(uint4*)(dst + 8) = wB;
        }
    }

    // kgen via MFMA: kg(196x49) = r_tile(196x64) @ wspan_g(64x49) + bias
    bf16x8 ra[4][2];
    #pragma unroll
    for (int mi = 0; mi < 4; ++mi) {    // preload all r fragments: one exposed latency
        int mt = mi * 4 + w;
        int mtc = mt < 13 ? mt : 12;
        int m  = mtc * 16 + (lane & 15);
        int mm = m < 196 ? m : 195;
        int ly = mm / TS, lx = mm % TS;
        size_t pix = ((size_t)(b * H_ + ty0 + ly)) * W_ + (tx0 + lx);
        const uint16_t* rp = r + pix * CR + (lane >> 4) * 8;
        ra[mi][0] = *(const bf16x8*)(rp);
        ra[mi][1] = *(const bf16x8*)(rp + 32);
    }
    #pragma unroll
    for (int mi = 0; mi < 4; ++mi) {
        int mt = mi * 4 + w;            // 13 row-tiles over 4 waves
        if (mt < 13) {
            f32x4 acc[4];
            #pragma unroll
            for (int nb = 0; nb < 4; ++nb)
                acc[nb] = (f32x4){bias[nb], bias[nb], bias[nb], bias[nb]};
            #pragma unroll
            for (int nb = 0; nb < 4; ++nb) {
                acc[nb] = __builtin_amdgcn_mfma_f32_16x16x32_bf16(ra[mi][0], bfr[0][nb], acc[nb], 0, 0, 0);
                acc[nb] = __builtin_amdgcn_mfma_f32_16x16x32_bf16(ra[mi][1], bfr[1][nb], acc[nb], 0, 0, 0);
            }
            int row = mt * 16 + (lane >> 4) * 4;
            if (row < 196) {
                #pragma unroll
                for (int nb = 0; nb < 4; ++nb) {
                    int n = nb * 16 + (lane & 15);
                    if (n < KK) {
                        int slot = n + n / 7;        // per-kh padded: kh*8 + kw
                        #pragma unroll
                        for (int rg = 0; rg < 4; ++rg) {
                            int rr  = row + rg;
                            int rho = (rr >> 1) + (rr & 1) * 98;  // even/odd row split
                            kg[rho * KGW + slot] = (uint16_t)f2bf(acc[nb][rg]);
                        }
                    }
                }
            }
        }
    }
    __syncthreads();

    // involution: 196 threads = (pixel-pair, 8-ch half); adjacent px share xs reads
    if (tid < 196) {
        int p = tid >> 1, h = tid & 1;
        int ty = p / 7, tx = (p % 7) * 2;
        const uint16_t* kgL = kg + p * KGW;          // even pixels: consecutive rows
        const uint16_t* kgR = kg + (98 + p) * KGW;   // odd pixels: consecutive rows

        f32x2 accL[4] = {{0,0},{0,0},{0,0},{0,0}};
        f32x2 accR[4] = {{0,0},{0,0},{0,0},{0,0}};
        #pragma unroll
        for (int kh = 0; kh < KS; ++kh) {
            uint4 aL = *(const uint4*)(kgL + kh * 8);
            uint4 aR = *(const uint4*)(kgR + kh * 8);
            const uint32_t kwL[4] = {aL.x, aL.y, aL.z, aL.w};
            const uint32_t kwR[4] = {aR.x, aR.y, aR.z, aR.w};
            const uint16_t* xrow = xs + ((ty + kh) * XSP + tx) * 16 + h * 8;
            #pragma unroll
            for (int j = 0; j < 8; ++j) {            // union of both 7-tap windows
                uint4 xw = *(const uint4*)(xrow + j * 16);
                float kvL = 0.f, kvR = 0.f;
                if (j < 7) kvL = (j & 1) ? bhi(kwL[j >> 1]) : blo(kwL[j >> 1]);
                if (j > 0) { int t = j - 1; kvR = (t & 1) ? bhi(kwR[t >> 1]) : blo(kwR[t >> 1]); }
                f32x2 kL = {kvL, kvL}, kR = {kvR, kvR};
                f32x2 x0 = {blo(xw.x), bhi(xw.x)};
                f32x2 x1 = {blo(xw.y), bhi(xw.y)};
                f32x2 x2 = {blo(xw.z), bhi(xw.z)};
                f32x2 x3 = {blo(xw.w), bhi(xw.w)};
                accL[0] = __builtin_elementwise_fma(kL, x0, accL[0]);
                accL[1] = __builtin_elementwise_fma(kL, x1, accL[1]);
                accL[2] = __builtin_elementwise_fma(kL, x2, accL[2]);
                accL[3] = __builtin_elementwise_fma(kL, x3, accL[3]);
                accR[0] = __builtin_elementwise_fma(kR, x0, accR[0]);
                accR[1] = __builtin_elementwise_fma(kR, x1, accR[1]);
                accR[2] = __builtin_elementwise_fma(kR, x2, accR[2]);
                accR[3] = __builtin_elementwise_fma(kR, x3, accR[3]);
            }
        }
        size_t pixL = ((size_t)(b * H_ + ty0 + ty)) * W_ + (tx0 + tx);
        float* opL = out + pixL * C_ + g * CG + h * 8;
        float* opR = opL + C_;
        *(float4*)(opL + 0) = make_float4(accL[0].x, accL[0].y, accL[1].x, accL[1].y);
        *(float4*)(opL + 4) = make_float4(accL[2].x, accL[2].y, accL[3].x, accL[3].y);
        *(float4*)(opR + 0) = make_float4(accR[0].x, accR[0].y, accR[1].x, accR[1].y);
        *(float4*)(opR + 4) = make_float4(accR[2].x, accR[2].y, accR[3].x, accR[3].y);
    }

    // ======== exit protocol: last block out resets counters for next graph replay ========
    if (tid == 0) {
        uint32_t old = __hip_atomic_fetch_add(&ctr[2], 1u, __ATOMIC_ACQ_REL, __HIP_MEMORY_SCOPE_AGENT);
        if (old == (uint32_t)(NBLK - 1)) {
            __hip_atomic_store(&ctr[0], 0u, __ATOMIC_RELAXED, __HIP_MEMORY_SCOPE_AGENT);
            __hip_atomic_store(&ctr[1], 0u, __ATOMIC_RELAXED, __HIP_MEMORY_SCOPE_AGENT);
            __hip_atomic_store(&ctr[2], 0u, __ATOMIC_RELEASE, __HIP_MEMORY_SCOPE_AGENT);
        }
    }
}

extern "C" void kernel_launch(void* const* d_in, const int* in_sizes, int n_in,
                              void* d_out, int out_size, void* d_ws, size_t ws_size,
                              hipStream_t stream) {
    const float* x        = (const float*)d_in[0];
    const float* w_reduce = (const float*)d_in[1];
    const float* gamma    = (const float*)d_in[2];
    const float* beta     = (const float*)d_in[3];
    const float* mean     = (const float*)d_in[4];
    const float* var      = (const float*)d_in[5];
    const float* w_span   = (const float*)d_in[6];
    const float* b_span   = (const float*)d_in[7];
    float* out = (float*)d_out;

    uint8_t* ws = (uint8_t*)d_ws;
    uint16_t* r_ws  = (uint16_t*)(ws + 0);          // 1605632 B
    uint16_t* wrp   = (uint16_t*)(ws + 1605632);    // 32768 B
    uint16_t* wpp   = (uint16_t*)(ws + 1638400);    // 131072 B
    float*    scale = (float*)   (ws + 1769472);    // 256 B
    float*    shift = (float*)   (ws + 1769728);    // 256 B
    uint8_t*  sync  = ws + 1769984;                 // 64 B: magic(8) + 3 counters

    hipLaunchKernelGGL(k_all, dim3(NBLK), dim3(256), 0, stream,
                       x, w_reduce, w_span, gamma, beta, mean, var, b_span,
                       r_ws, wrp, wpp, scale, shift, sync, out);
}